// Round 6
// baseline (319.776 us; speedup 1.0000x reference)
//
#include <hip/hip_runtime.h>
#include <stdint.h>

#define N_THRESH 100
#define NBINS 101
#define NWORDS 51                        // 2 bins per u32 word, [pos:8|cnt:8] per half
#define STEP_ELEMS 1024                  // elements per DMA step per block
#define STEPS 16
#define TILE_ELEMS (STEP_ELEMS * STEPS)  // 16384 per tile

typedef __attribute__((address_space(3))) uint32_t lds_u32_t;
typedef __attribute__((address_space(1))) uint32_t glob_u32_t;

// ---------------------------------------------------------------------------
// Kernel 0: zero the workspace histogram (d_ws is poisoned 0xAA every call).
// ---------------------------------------------------------------------------
__global__ void zero_ws_kernel(unsigned long long* __restrict__ ws) {
    int i = threadIdx.x;
    if (i < NBINS) ws[i] = 0ull;
}

// ---------------------------------------------------------------------------
// Branch-free exact bin (absmax 0.0 across R1-R5): cnt = searchsorted(
// thresholds, v, 'left'), thresholds[k] = float32(double(k)*0.01).
// e = trunc(fl(v*100)) is within 1 of the answer, so
// cnt = e + (t_e < v) + (t_{e+1} < v) exactly. All in registers.
// ---------------------------------------------------------------------------
__device__ __forceinline__ int bin_of(float v) {
    int e = (int)(v * 100.0f);
    e = e < 0 ? 0 : (e > 99 ? 99 : e);
    double ed = (double)e * 0.01;
    float t0 = (float)ed;
    float t1 = (float)(ed + 0.01);
    int c = e + (t0 < v ? 1 : 0) + (t1 < v ? 1 : 0);
    return c > N_THRESH ? N_THRESH : c;
}

// Async DMA: each wave stages its 256-element slice of the step (1KB pred +
// 1KB gt) with one width=16 global_load_lds each (dest = wave-uniform base,
// HW adds lane*16 — matches the contiguous source layout).
__device__ __forceinline__ void stage(const float* __restrict__ pred,
                                      const int* __restrict__ gt,
                                      float* spb, int* sgb,
                                      int ebase, int wave, int lane) {
    const float* srcp = pred + ebase + wave * 256 + lane * 4;
    const int*   srcg = gt   + ebase + wave * 256 + lane * 4;
    __builtin_amdgcn_global_load_lds((glob_u32_t*)srcp,
                                     (lds_u32_t*)(spb + wave * 256), 16, 0, 0);
    __builtin_amdgcn_global_load_lds((glob_u32_t*)srcg,
                                     (lds_u32_t*)(sgb + wave * 256), 16, 0, 0);
}

// ---------------------------------------------------------------------------
// Kernel 1: streaming histogram with PER-LANE PRIVATE columns, no LDS atomics.
// hist[wave][word][lane]: only lane touches its column -> plain u32 += (DS
// read-add-write). Bank = lane mod 32 for any bin -> fixed 2-way (free).
// Packing: word = bin>>1, half = bin&1, cell half = [pos:8|cnt:8]; per-lane
// per-tile increments <= 64 < 255 -> exact. Fold per tile into u32 partials.
// LDS: 52.2K hist + 16K dbuf staging + 0.8K partials = 69.4K -> 2 blocks/CU.
// ---------------------------------------------------------------------------
__global__ __launch_bounds__(256) void hist_kernel(
        const float* __restrict__ pred,
        const int* __restrict__ gt,
        unsigned long long* __restrict__ ws,
        int n) {
    __shared__ uint32_t hist[4][NWORDS][64];            // 52224 B
    __shared__ __align__(16) float sp[2][STEP_ELEMS];   // 8192 B
    __shared__ __align__(16) int   sg[2][STEP_ELEMS];   // 8192 B
    __shared__ uint32_t pcnt[NBINS], ppos[NBINS];       // 808 B

    const int tid  = threadIdx.x;
    const int wave = tid >> 6;
    const int lane = tid & 63;
    uint32_t* __restrict__ hw = &hist[wave][0][0];

    if (tid < NBINS) { pcnt[tid] = 0u; ppos[tid] = 0u; }

    const int tiles = (n + TILE_ELEMS - 1) / TILE_ELEMS;
    for (int t = blockIdx.x; t < tiles; t += gridDim.x) {
        const int base = t * TILE_ELEMS;
        // zero this wave's private histogram (bank = lane mod 32, 2-way free)
        for (int i = lane; i < NWORDS * 64; i += 64) hw[i] = 0u;
        __syncthreads();

        const int limit = (n - base < TILE_ELEMS) ? (n - base) : TILE_ELEMS;
        if (limit == TILE_ELEMS) {
            stage(pred, gt, sp[0], sg[0], base, wave, lane);
            __syncthreads();   // buf0 landed
            for (int s = 0; s < STEPS; ++s) {
                const int b = s & 1;
                if (s + 1 < STEPS)
                    stage(pred, gt, sp[b ^ 1], sg[b ^ 1],
                          base + (s + 1) * STEP_ELEMS, wave, lane);
                float4 p = ((const float4*)sp[b])[tid];
                int4   g = ((const int4*)sg[b])[tid];
                {   // 4 sequential private RMWs (in-order DS, race-free)
                    int c0 = bin_of(p.x), c1 = bin_of(p.y);
                    int c2 = bin_of(p.z), c3 = bin_of(p.w);
                    hist[wave][c0 >> 1][lane] +=
                        (1u | ((uint32_t)(g.x != 0) << 8)) << ((c0 & 1) * 16);
                    hist[wave][c1 >> 1][lane] +=
                        (1u | ((uint32_t)(g.y != 0) << 8)) << ((c1 & 1) * 16);
                    hist[wave][c2 >> 1][lane] +=
                        (1u | ((uint32_t)(g.z != 0) << 8)) << ((c2 & 1) * 16);
                    hist[wave][c3 >> 1][lane] +=
                        (1u | ((uint32_t)(g.w != 0) << 8)) << ((c3 & 1) * 16);
                }
                __syncthreads();  // prefetch landed + buffer reads done
            }
        } else {
            // tail tile (empty at N = 2^25): plain loads, <=64 elems per lane
            for (int k = base + tid; k < base + limit; k += 256) {
                int c = bin_of(pred[k]);
                hist[wave][c >> 1][lane] +=
                    (1u | ((uint32_t)(gt[k] != 0) << 8)) << ((c & 1) * 16);
            }
            __syncthreads();
        }

        // fold this tile: lane w (w < 51) sums its wave's word w over 64
        // columns, staggered start -> 2-way banks only
        if (lane < NWORDS) {
            uint32_t c0 = 0, p0 = 0, c1 = 0, p1 = 0;
            for (int c = 0; c < 64; ++c) {
                uint32_t v = hist[wave][lane][(c + lane) & 63];
                c0 += v & 0xffu;         p0 += (v >> 8) & 0xffu;
                c1 += (v >> 16) & 0xffu; p1 += v >> 24;
            }
            const int b0 = lane * 2, b1 = lane * 2 + 1;
            atomicAdd(&pcnt[b0], c0);
            atomicAdd(&ppos[b0], p0);
            if (b1 < NBINS) {            // half 1 of word 50 = bin 101: unused
                atomicAdd(&pcnt[b1], c1);
                atomicAdd(&ppos[b1], p1);
            }
        }
        __syncthreads();   // partials folded before hist re-zeroed next tile
    }

    if (tid < NBINS) {
        unsigned long long s =
            ((unsigned long long)ppos[tid] << 32) | (unsigned long long)pcnt[tid];
        if (s) atomicAdd(&ws[tid], s);
    }
}

// ---------------------------------------------------------------------------
// Kernel 2: suffix sums + IoU. One block, trivial cost.
// out[0:100] = thresholds, out[100:200] = ious.
// ---------------------------------------------------------------------------
__global__ void finalize_kernel(const unsigned long long* __restrict__ ws,
                                float* __restrict__ out) {
    __shared__ unsigned int pos[NBINS], all[NBINS];
    int k = threadIdx.x;
    if (k < NBINS) {
        unsigned long long h = ws[k];
        pos[k] = (unsigned int)(h >> 32);
        all[k] = (unsigned int)(h & 0xffffffffull);
    }
    __syncthreads();
    if (k < N_THRESH) {
        out[k] = (float)((double)k * 0.01);
        unsigned long long tp = 0, pp = 0, ngt = 0;
        for (int c = k + 1; c <= N_THRESH; ++c) { tp += pos[c]; pp += all[c]; }
        for (int c = 0; c <= N_THRESH; ++c) ngt += pos[c];
        long long uni = (long long)(pp + ngt - tp);   // TP + FP + FN
        double iou = (uni > 0) ? (double)tp / (double)uni : 0.0;
        out[N_THRESH + k] = (float)iou;
    }
}

// ---------------------------------------------------------------------------
extern "C" void kernel_launch(void* const* d_in, const int* in_sizes, int n_in,
                              void* d_out, int out_size, void* d_ws, size_t ws_size,
                              hipStream_t stream) {
    const float* pred = (const float*)d_in[0];
    const int*   gt   = (const int*)d_in[1];
    float* out = (float*)d_out;
    unsigned long long* ws = (unsigned long long*)d_ws;
    int n = in_sizes[0];

    zero_ws_kernel<<<1, 128, 0, stream>>>(ws);
    // 512 blocks = 2 resident/CU (69.4 KB LDS) x 256 CUs; 4 tiles per block
    // at N = 2^25; per-block final global atomics = 101 x 512 (low contention)
    hist_kernel<<<512, 256, 0, stream>>>(pred, gt, ws, n);
    finalize_kernel<<<1, 128, 0, stream>>>(ws, out);
}

// Round 7
// 285.898 us; speedup vs baseline: 1.1185x; 1.1185x over previous
//
#include <hip/hip_runtime.h>
#include <stdint.h>

#define N_THRESH 100
#define NBINS 101
#define NWORDS 51   // 2 bins per u32 word; per half: [pos:8 | cnt:8]

// ---------------------------------------------------------------------------
// Kernel 0: zero the workspace histogram (d_ws is poisoned 0xAA every call).
// ---------------------------------------------------------------------------
__global__ void zero_ws_kernel(unsigned long long* __restrict__ ws) {
    int i = threadIdx.x;
    if (i < NBINS) ws[i] = 0ull;
}

// ---------------------------------------------------------------------------
// Branch-free exact bin (absmax 0.0 across R1-R6): cnt = searchsorted(
// thresholds, v, 'left'), thresholds[k] = float32(double(k)*0.01).
// e = trunc(fl(v*100)) is within 1 of the answer, so
// cnt = e + (t_e < v) + (t_{e+1} < v) exactly. All in registers.
// ---------------------------------------------------------------------------
__device__ __forceinline__ int bin_of(float v) {
    int e = (int)(v * 100.0f);
    e = e < 0 ? 0 : (e > 99 ? 99 : e);
    double ed = (double)e * 0.01;
    float t0 = (float)ed;
    float t1 = (float)(ed + 0.01);
    int c = e + (t0 < v ? 1 : 0) + (t1 < v ? 1 : 0);
    return c > N_THRESH ? N_THRESH : c;
}

// ---------------------------------------------------------------------------
// Kernel 1: streaming histogram. Per-lane PRIVATE columns, NO atomics, NO
// barriers, NO staging in the main loop:
//   hist[wave][word][lane]: only (wave,lane) touches its column -> plain
//   u32 += is race-free. Bank = lane mod 32 for any bin -> fixed 2-way (free).
//   DS RMW latency chains overlap across 12 resident waves/CU (3 blocks/CU),
//   unlike ds_add atomics which measured ~118 cyc/wave-instr unpipelined
//   (the R1-R5 wall).
// Packing: word = bin>>1, halves [pos:8|cnt:8]. Grid sized so each thread
// handles <= 200 elements -> 8-bit counters exact even if all-same-bin.
// Fold once per block at the end.
// ---------------------------------------------------------------------------
__global__ __launch_bounds__(256) void hist_kernel(
        const float* __restrict__ pred,
        const int* __restrict__ gt,
        unsigned long long* __restrict__ ws,
        int n) {
    __shared__ uint32_t hist[4][NWORDS][64];        // 52224 B
    __shared__ uint32_t pcnt[NBINS], ppos[NBINS];   // 808 B

    const int tid  = threadIdx.x;
    const int wave = tid >> 6;
    const int lane = tid & 63;

    // zero this wave's private histogram (col = lane: 2-way banks, free)
    for (int i = lane; i < NWORDS * 64; i += 64) (&hist[wave][0][0])[i] = 0u;
    if (tid < NBINS) { pcnt[tid] = 0u; ppos[tid] = 0u; }

    const int nvec = n >> 2;
    const float4* __restrict__ p4 = (const float4*)pred;
    const int4*   __restrict__ g4 = (const int4*)gt;
    const int gsz = gridDim.x * blockDim.x;

    int i = blockIdx.x * blockDim.x + tid;
    if (i < nvec) {
        // software pipeline: next iteration's loads issue before current RMWs
        float4 p = p4[i];
        int4   g = g4[i];
        for (int j = i + gsz; j < nvec; j += gsz) {
            float4 pn = p4[j];
            int4   gn = g4[j];
            int c0 = bin_of(p.x), c1 = bin_of(p.y);
            int c2 = bin_of(p.z), c3 = bin_of(p.w);
            hist[wave][c0 >> 1][lane] +=
                (1u | ((uint32_t)(g.x != 0) << 8)) << ((c0 & 1) * 16);
            hist[wave][c1 >> 1][lane] +=
                (1u | ((uint32_t)(g.y != 0) << 8)) << ((c1 & 1) * 16);
            hist[wave][c2 >> 1][lane] +=
                (1u | ((uint32_t)(g.z != 0) << 8)) << ((c2 & 1) * 16);
            hist[wave][c3 >> 1][lane] +=
                (1u | ((uint32_t)(g.w != 0) << 8)) << ((c3 & 1) * 16);
            p = pn; g = gn;
        }
        int c0 = bin_of(p.x), c1 = bin_of(p.y);
        int c2 = bin_of(p.z), c3 = bin_of(p.w);
        hist[wave][c0 >> 1][lane] +=
            (1u | ((uint32_t)(g.x != 0) << 8)) << ((c0 & 1) * 16);
        hist[wave][c1 >> 1][lane] +=
            (1u | ((uint32_t)(g.y != 0) << 8)) << ((c1 & 1) * 16);
        hist[wave][c2 >> 1][lane] +=
            (1u | ((uint32_t)(g.z != 0) << 8)) << ((c2 & 1) * 16);
        hist[wave][c3 >> 1][lane] +=
            (1u | ((uint32_t)(g.w != 0) << 8)) << ((c3 & 1) * 16);
    }

    // scalar tail (n not multiple of 4) — empty for N = 2^25
    if (blockIdx.x == 0 && tid == 0) {
        for (int k = nvec << 2; k < n; ++k) {
            int c = bin_of(pred[k]);
            hist[0][c >> 1][0] +=
                (1u | ((uint32_t)(gt[k] != 0) << 8)) << ((c & 1) * 16);
        }
    }

    __syncthreads();
    // fold: lane w (<51) sums its wave's word w over 64 columns, staggered
    // start -> ~2 lanes/bank only
    if (lane < NWORDS) {
        uint32_t c0 = 0, p0 = 0, c1 = 0, p1 = 0;
        for (int c = 0; c < 64; ++c) {
            uint32_t v = hist[wave][lane][(c + lane) & 63];
            c0 += v & 0xffu;         p0 += (v >> 8) & 0xffu;
            c1 += (v >> 16) & 0xffu; p1 += v >> 24;
        }
        const int b0 = lane * 2, b1 = lane * 2 + 1;
        atomicAdd(&pcnt[b0], c0);
        atomicAdd(&ppos[b0], p0);
        if (b1 < NBINS) {               // half 1 of word 50 = bin 101: unused
            atomicAdd(&pcnt[b1], c1);
            atomicAdd(&ppos[b1], p1);
        }
    }
    __syncthreads();

    if (tid < NBINS) {
        unsigned long long s =
            ((unsigned long long)ppos[tid] << 32) | (unsigned long long)pcnt[tid];
        if (s) atomicAdd(&ws[tid], s);
    }
}

// ---------------------------------------------------------------------------
// Kernel 2: suffix sums + IoU. One block, trivial cost.
// out[0:100] = thresholds, out[100:200] = ious.
// ---------------------------------------------------------------------------
__global__ void finalize_kernel(const unsigned long long* __restrict__ ws,
                                float* __restrict__ out) {
    __shared__ unsigned int pos[NBINS], all[NBINS];
    int k = threadIdx.x;
    if (k < NBINS) {
        unsigned long long h = ws[k];
        pos[k] = (unsigned int)(h >> 32);
        all[k] = (unsigned int)(h & 0xffffffffull);
    }
    __syncthreads();
    if (k < N_THRESH) {
        out[k] = (float)((double)k * 0.01);
        unsigned long long tp = 0, pp = 0, ngt = 0;
        for (int c = k + 1; c <= N_THRESH; ++c) { tp += pos[c]; pp += all[c]; }
        for (int c = 0; c <= N_THRESH; ++c) ngt += pos[c];
        long long uni = (long long)(pp + ngt - tp);   // TP + FP + FN
        double iou = (uni > 0) ? (double)tp / (double)uni : 0.0;
        out[N_THRESH + k] = (float)iou;
    }
}

// ---------------------------------------------------------------------------
extern "C" void kernel_launch(void* const* d_in, const int* in_sizes, int n_in,
                              void* d_out, int out_size, void* d_ws, size_t ws_size,
                              hipStream_t stream) {
    const float* pred = (const float*)d_in[0];
    const int*   gt   = (const int*)d_in[1];
    float* out = (float*)d_out;
    unsigned long long* ws = (unsigned long long*)d_ws;
    int n = in_sizes[0];

    zero_ws_kernel<<<1, 128, 0, stream>>>(ws);
    // 768 blocks = 3 resident/CU (53.0 KB LDS) x 256 CUs; <=172 elements per
    // thread at N = 2^25 -> 8-bit packed counters exact unconditionally.
    // Guard: grow grid if n ever exceeds the 200-elem/thread exactness bound.
    int grid = 768;
    int need = (n + 51199) / 51200;      // grid s.t. elems/thread <= 200
    if (need > grid) grid = need;
    hist_kernel<<<grid, 256, 0, stream>>>(pred, gt, ws, n);
    finalize_kernel<<<1, 128, 0, stream>>>(ws, out);
}